// Round 15
// baseline (301.972 us; speedup 1.0000x reference)
//
#include <hip/hip_runtime.h>
#include <hip/hip_bf16.h>
#include <math.h>

#define B_ 8
#define N_ 2048
#define D_ 128
#define E_ 256
#define K_ 16
#define LN_EPS 1e-5f

typedef short bf16x8 __attribute__((ext_vector_type(8)));
typedef float f32x4 __attribute__((ext_vector_type(4)));
typedef float f32x2 __attribute__((ext_vector_type(2)));

// ---------------------------------------------------------------------------
// Reference-matching f32 distance (expanded form, no FMA contraction).
// ---------------------------------------------------------------------------
__device__ __forceinline__ float sq3_ref(float x, float y, float z) {
#pragma clang fp contract(off)
    float s = x * x + y * y;
    s = s + z * z;
    return s;
}
__device__ __forceinline__ float d2_ref(float qx, float qy, float qz, float sqq,
                                        float mx, float my, float mz, float sqm) {
#pragma clang fp contract(off)
    float dot = mx * qx + my * qy;
    dot = dot + mz * qz;
    float t1 = sqq + sqm;
    float t2 = 2.0f * dot;
    float d2 = t1 - t2;
    return d2 > 0.0f ? d2 : 0.0f;
}

// pack two f32 -> bf16x2 dword (compiler fuses to v_cvt_pk_bf16_f32)
__device__ __forceinline__ unsigned pack2(float a, float b) {
    union { __hip_bfloat162 h2; unsigned u; } cv;
    cv.h2 = __float22bfloat162_rn(float2{a, b});
    return cv.u;
}

// tanh-form GELU pair via sigmoid identity, f32x2 vector form (v_pk_* ops)
__device__ __forceinline__ f32x2 gelu2(f32x2 v) {
    const f32x2 w = v * v;
    f32x2 inner = w * 0.044715f;
    inner.x += 1.0f; inner.y += 1.0f;
    const f32x2 ue = (v * -2.3022083f) * inner;      // -2u*log2e
    f32x2 t;
    t.x = __builtin_amdgcn_exp2f(ue.x);
    t.y = __builtin_amdgcn_exp2f(ue.y);
    f32x2 den = t;
    den.x += 1.0f; den.y += 1.0f;
    f32x2 r;
    r.x = __builtin_amdgcn_rcpf(den.x);
    r.y = __builtin_amdgcn_rcpf(den.y);
    return v * r;
}

// max over the 16 contiguous lanes of a DPP row (e = lane&15), VALU-only.
__device__ __forceinline__ float dpp_rowmax16(float v) {
    int x = __float_as_int(v);
    v = fmaxf(v, __int_as_float(__builtin_amdgcn_mov_dpp(x, 0xB1, 0xF, 0xF, true)));
    x = __float_as_int(v);
    v = fmaxf(v, __int_as_float(__builtin_amdgcn_mov_dpp(x, 0x4E, 0xF, 0xF, true)));
    x = __float_as_int(v);
    v = fmaxf(v, __int_as_float(__builtin_amdgcn_mov_dpp(x, 0x141, 0xF, 0xF, true)));
    x = __float_as_int(v);
    v = fmaxf(v, __int_as_float(__builtin_amdgcn_mov_dpp(x, 0x140, 0xF, 0xF, true)));
    return v;
}

// ---------------------------------------------------------------------------
// Kernel 1 (fused prep), 512 threads/block, heterogeneous grid (as R14):
//   blocks [0, 2048)    : kNN top-16 radix select
//   blocks [2048, 2096) : W1/W2/W3 -> bf16 MFMA A-fragment prepack
//   blocks [2096, 2224) : shortcut out = x @ Ws + bs (MFMA, inline A-pack)
// ---------------------------------------------------------------------------
__global__ __launch_bounds__(512) void prep_kernel(
    const float* __restrict__ coords, const float* __restrict__ x,
    const float* __restrict__ W1, const float* __restrict__ W2,
    const float* __restrict__ W3, const float* __restrict__ Ws,
    const float* __restrict__ bs,
    int* __restrict__ knn_out, short* __restrict__ WF, float* __restrict__ out)
{
    __shared__ float smem[4 * N_ + 8];
    const int bid = blockIdx.x;
    const int tid = threadIdx.x;

    if (bid < 2048) {
        // ================= kNN top-16 radix select =================
        float (*lc)[N_] = (float(*)[N_])smem;
        float* lsq = smem + 3 * N_;
        int* cnt = (int*)(smem + 4 * N_);
        const int wave = tid >> 6;
        const int lane = tid & 63;
        const int p = bid * 8 + wave;
        const int b = p >> 11;
        const int n0 = p & (N_ - 1);
        const float* cb = coords + (size_t)b * N_ * 3;
        for (int i = tid; i < N_ * 3; i += 512) {
            int n = i / 3, c = i - 3 * n;
            lc[c][n] = cb[i];
        }
        __syncthreads();
        for (int n = tid; n < N_; n += 512) lsq[n] = sq3_ref(lc[0][n], lc[1][n], lc[2][n]);
        __syncthreads();

        const float qx = lc[0][n0], qy = lc[1][n0], qz = lc[2][n0], sqq = lsq[n0];
        unsigned key[32];
#pragma unroll
        for (int j = 0; j < 32; ++j) {
            const int m = j * 64 + lane;
            key[j] = __float_as_uint(d2_ref(qx, qy, qz, sqq, lc[0][m], lc[1][m], lc[2][m], lsq[m]));
        }

        unsigned prefix = 0;
        int rem = K_, setc = N_, bshift = 0;
        bool bounded = false;
        for (int bit = 31; bit >= 0; --bit) {
            const unsigned want = prefix << 1;
            int c = 0;
#pragma unroll
            for (int j = 0; j < 32; ++j) c += ((key[j] >> bit) == want) ? 1 : 0;
            for (int off = 1; off < 64; off <<= 1) c += __shfl_xor(c, off, 64);
            if (rem <= c) { prefix = want; setc = c; }
            else          { prefix = want | 1u; rem -= c; setc -= c; }
            bshift = bit;
            if (setc == rem) { bounded = true; break; }
        }

        if (lane == 0) cnt[wave] = 0;
        int* op = knn_out + (size_t)p * K_;
        const unsigned long long BE = bounded ? (((unsigned long long)prefix + 1ull) << bshift)
                                              : (unsigned long long)prefix;
#pragma unroll
        for (int j = 0; j < 32; ++j) {
            if ((unsigned long long)key[j] < BE) {
                int s = atomicAdd(&cnt[wave], 1);
                op[s] = j * 64 + lane;
            }
        }
        if (!bounded) {
            const unsigned V = prefix;
#pragma unroll
            for (int j = 0; j < 32; ++j) {
                if (rem > 0) {
                    unsigned long long mask = __ballot(key[j] == V);
                    int below = __popcll(mask & ((1ull << lane) - 1ull));
                    if (key[j] == V && below < rem) {
                        int s = atomicAdd(&cnt[wave], 1);
                        op[s] = j * 64 + lane;
                    }
                    rem -= __popcll(mask);
                }
            }
        }
    } else if (bid < 2096) {
        // ================= W prepack: layers only (384 units, 8 per block) =====
        const int unit = (bid - 2048) * 8 + (tid >> 6);  // 0..383
        const int lane = tid & 63;
        const int g = lane >> 4, e = lane & 15;
        const int L = unit >> 7;
        const int t = unit & 127;                        // t = kt*16 + mt
        const int kt = t >> 4, mt = t & 15;
        const float* W = (L == 0) ? W1 : (L == 1) ? W2 : W3;
        const int f = 16 * mt + e;
        unsigned v[4];
#pragma unroll
        for (int i2 = 0; i2 < 4; ++i2) {
            const int k = 32 * kt + 8 * g + 2 * i2;
            v[i2] = pack2(W[(size_t)k * E_ + f], W[(size_t)(k + 1) * E_ + f]);
        }
        uint4 u; u.x = v[0]; u.y = v[1]; u.z = v[2]; u.w = v[3];
        *reinterpret_cast<uint4*>(WF + ((size_t)unit * 64 + lane) * 8) = u;
    } else {
        // ================= shortcut: out = x @ Ws + bs (MFMA, inline A-pack) ===
        const int wave = tid >> 6;
        const int lane = tid & 63;
        const int e = lane & 15;
        const int g = lane >> 4;
        const int p0 = ((bid - 2096) * 8 + wave) * 16;   // 16 points per wave
        const float* xr = x + (size_t)(p0 + e) * D_;

        f32x4 acc[16];
        const f32x4 z4 = {0.f, 0.f, 0.f, 0.f};
#pragma unroll
        for (int mt = 0; mt < 16; ++mt) acc[mt] = z4;

#pragma unroll
        for (int kt = 0; kt < 4; ++kt) {
            const float4 xa = *(const float4*)(xr + kt * 32 + g * 8);
            const float4 xb = *(const float4*)(xr + kt * 32 + g * 8 + 4);
            union { unsigned u[4]; bf16x8 v; } bx;
            bx.u[0] = pack2(xa.x, xa.y); bx.u[1] = pack2(xa.z, xa.w);
            bx.u[2] = pack2(xb.x, xb.y); bx.u[3] = pack2(xb.z, xb.w);
            const float* Wsrc = Ws + (size_t)(32 * kt + 8 * g) * E_ + e;
#pragma unroll
            for (int mt = 0; mt < 16; ++mt) {
                const float* wp = Wsrc + 16 * mt;
                float w[8];
#pragma unroll
                for (int i = 0; i < 8; ++i) w[i] = wp[(size_t)i * E_];
                union { unsigned u[4]; bf16x8 v; } a;
                a.u[0] = pack2(w[0], w[1]); a.u[1] = pack2(w[2], w[3]);
                a.u[2] = pack2(w[4], w[5]); a.u[3] = pack2(w[6], w[7]);
                acc[mt] = __builtin_amdgcn_mfma_f32_16x16x32_bf16(a.v, bx.v, acc[mt], 0, 0, 0);
            }
        }
#pragma unroll
        for (int mt = 0; mt < 16; ++mt) {
            const float4 bsv = *(const float4*)(bs + 16 * mt + 4 * g);
            float4 o;
            o.x = acc[mt][0] + bsv.x; o.y = acc[mt][1] + bsv.y;
            o.z = acc[mt][2] + bsv.z; o.w = acc[mt][3] + bsv.w;
            *(float4*)(out + (size_t)(p0 + e) * E_ + 16 * mt + 4 * g) = o;
        }
    }
}

// ---------------------------------------------------------------------------
// Kernel 2: fused edge-MLP, WAVE-PAIR mt-split, BARRIER-LIGHT:
// A-fragments read DIRECTLY from global WF (L2-resident, fragment-linear,
// coalesced base+imm addressing) -> no Wbuf, no per-phase vmcnt(0)+barriers.
// Barriers remain only at: build (1), Xch per layer (3), H-transition (2),
// epilogue (1). LDS = 32(Hl) + 1(Xch) + 9(Pl) = 42 KiB; launch_bounds(256,3).
// ---------------------------------------------------------------------------
__global__ __launch_bounds__(256, 3) void edgeconv_mfma(
    const float* __restrict__ x, const int* __restrict__ knn,
    const short* __restrict__ WF,
    const float* __restrict__ b1, const float* __restrict__ g1, const float* __restrict__ be1,
    const float* __restrict__ b2, const float* __restrict__ g2, const float* __restrict__ be2,
    const float* __restrict__ b3, const float* __restrict__ g3, const float* __restrict__ be3,
    float* __restrict__ out)
{
    __shared__ short Hl[2][2][4096];    // 32 KiB: [pair][point][16e x 256f bf16] swizzled
    __shared__ float4 Xch[2][2][16];    // 1 KiB: LN partial exchange
    __shared__ float Pl[9 * 256];       // 9 KiB: b1,g1,be1,b2,g2,be2,b3,g3,be3
    const int tid  = threadIdx.x;
    const int wave = tid >> 6;
    const int lane = tid & 63;
    const int wq = wave & 1;            // parity within pair (feature-half owner)
    const int pr = wave >> 1;           // pair index
    const int e = lane & 15;
    const int g = lane >> 4;
    const int p = blockIdx.x * 4 + wave;   // own point
    const int b = p >> 11;
    const int n = p & (N_ - 1);
    const unsigned swz = (unsigned)((e & 7) << 4);
    char* Hown = (char*)&Hl[pr][wq][0];
    char* Hp0  = (char*)&Hl[pr][0][0];
    char* Hp1  = (char*)&Hl[pr][1][0];

    // stage LN params once per block (visible after the build barrier)
    {
        const float* srcs[9] = {b1, g1, be1, b2, g2, be2, b3, g3, be3};
#pragma unroll
        for (int a = 0; a < 9; ++a) Pl[a * 256 + tid] = srcs[a][tid];
    }

    // ---- edge build (own point): H[e][0:128]=central, H[e][128:256]=nbr-central
    {
        const float4* xr = (const float4*)(x + ((size_t)b * N_ + n) * D_);
        const int nb = knn[(size_t)p * K_ + e];
        const float4* nr = (const float4*)(x + ((size_t)b * N_ + nb) * D_);
#pragma unroll
        for (int c2 = 0; c2 < 8; ++c2) {
            const float4 cv = xr[8 * g + c2];
            const float4 nv = nr[8 * g + c2];
            const int base = (e << 9) + (g << 6) + (c2 << 3);
            *(uint2*)(Hown + (base ^ swz)) = make_uint2(pack2(cv.x, cv.y), pack2(cv.z, cv.w));
            *(uint2*)(Hown + ((base + 256) ^ swz)) =
                make_uint2(pack2(nv.x - cv.x, nv.y - cv.y), pack2(nv.z - cv.z, nv.w - cv.w));
        }
    }
    __syncthreads();                     // H + Pl visible to the pair / block

    f32x4 acc0[8], acc1[8];             // [mtl] for point0 / point1
    const f32x4 z4 = {0.f, 0.f, 0.f, 0.f};

    for (int L = 0; L < 3; ++L) {
        const float* PlL = &Pl[L * 768];
#pragma unroll
        for (int mtl = 0; mtl < 8; ++mtl) { acc0[mtl] = z4; acc1[mtl] = z4; }

        // A base for this wave's feature-half: fragment (L,kt, wq*8+mtl)
        const short* AL = WF + (((size_t)(L * 128 + wq * 8)) << 9);

        for (int kt = 0; kt < 8; ++kt) {
            const int offB = (int)((unsigned)((e << 9) + (kt << 6) + (g << 4)) ^ swz);
            const bf16x8 Bc0 = *(const bf16x8*)(Hp0 + offB);
            const bf16x8 Bc1 = *(const bf16x8*)(Hp1 + offB);
            const short* Ak = AL + ((size_t)kt << 13);     // +16*512 shorts per kt
            __builtin_amdgcn_s_setprio(1);
#pragma unroll
            for (int mtl = 0; mtl < 8; ++mtl) {
                const bf16x8 a = *(const bf16x8*)(Ak + (mtl << 9) + (lane << 3));
                acc0[mtl] = __builtin_amdgcn_mfma_f32_16x16x32_bf16(a, Bc0, acc0[mtl], 0, 0, 0);
                acc1[mtl] = __builtin_amdgcn_mfma_f32_16x16x32_bf16(a, Bc1, acc1[mtl], 0, 0, 0);
            }
            __builtin_amdgcn_s_setprio(0);
        }

        // ---- LN pass 1: bias + partial sums (pk form) ----
        f32x2 s2_0 = {0.f, 0.f}, q2_0 = {0.f, 0.f};
        f32x2 s2_1 = {0.f, 0.f}, q2_1 = {0.f, 0.f};
#pragma unroll
        for (int mtl = 0; mtl < 8; ++mtl) {
            const int mtg = (wq << 3) + mtl;
            const float4 bv = *(const float4*)(PlL + mtg * 16 + (g << 2));
            const f32x2 blo = {bv.x, bv.y}, bhi = {bv.z, bv.w};
            f32x2 a0lo = {acc0[mtl][0], acc0[mtl][1]};
            f32x2 a0hi = {acc0[mtl][2], acc0[mtl][3]};
            f32x2 a1lo = {acc1[mtl][0], acc1[mtl][1]};
            f32x2 a1hi = {acc1[mtl][2], acc1[mtl][3]};
            a0lo = a0lo + blo; a0hi = a0hi + bhi;
            a1lo = a1lo + blo; a1hi = a1hi + bhi;
            s2_0 = s2_0 + a0lo; s2_0 = s2_0 + a0hi;
            q2_0 = q2_0 + a0lo * a0lo; q2_0 = q2_0 + a0hi * a0hi;
            s2_1 = s2_1 + a1lo; s2_1 = s2_1 + a1hi;
            q2_1 = q2_1 + a1lo * a1lo; q2_1 = q2_1 + a1hi * a1hi;
            acc0[mtl][0] = a0lo.x; acc0[mtl][1] = a0lo.y;
            acc0[mtl][2] = a0hi.x; acc0[mtl][3] = a0hi.y;
            acc1[mtl][0] = a1lo.x; acc1[mtl][1] = a1lo.y;
            acc1[mtl][2] = a1hi.x; acc1[mtl][3] = a1hi.y;
        }
        float s0 = s2_0.x + s2_0.y, q0 = q2_0.x + q2_0.y;
        float s1 = s2_1.x + s2_1.y, q1 = q2_1.x + q2_1.y;
        s0 += __shfl_xor(s0, 16, 64); s0 += __shfl_xor(s0, 32, 64);
        q0 += __shfl_xor(q0, 16, 64); q0 += __shfl_xor(q0, 32, 64);
        s1 += __shfl_xor(s1, 16, 64); s1 += __shfl_xor(s1, 32, 64);
        q1 += __shfl_xor(q1, 16, 64); q1 += __shfl_xor(q1, 32, 64);
        if (lane < 16) Xch[pr][wq][e] = make_float4(s0, q0, s1, q1);
        __syncthreads();
        const float4 oX = Xch[pr][wq ^ 1][e];
        const float mu0 = (s0 + oX.x) * (1.0f / 256.0f);
        const float var0 = fmaf(-mu0, mu0, (q0 + oX.y) * (1.0f / 256.0f));
        const float rstd0 = rsqrtf(var0 + LN_EPS);
        const float mu1 = (s1 + oX.z) * (1.0f / 256.0f);
        const float var1 = fmaf(-mu1, mu1, (q1 + oX.w) * (1.0f / 256.0f));
        const float rstd1 = rsqrtf(var1 + LN_EPS);

        // ---- LN pass 2 + GELU (pk form) ----
#pragma unroll
        for (int mtl = 0; mtl < 8; ++mtl) {
            const int mtg = (wq << 3) + mtl;
            const float4 gv  = *(const float4*)(PlL + 256 + mtg * 16 + (g << 2));
            const float4 bev = *(const float4*)(PlL + 512 + mtg * 16 + (g << 2));
            const f32x2 glo = {gv.x, gv.y}, ghi = {gv.z, gv.w};
            const f32x2 belo = {bev.x, bev.y}, behi = {bev.z, bev.w};
            const f32x2 A0lo = glo * rstd0, A0hi = ghi * rstd0;
            const f32x2 C0lo = A0lo * (-mu0) + belo, C0hi = A0hi * (-mu0) + behi;
            const f32x2 v0lo = {acc0[mtl][0], acc0[mtl][1]};
            const f32x2 v0hi = {acc0[mtl][2], acc0[mtl][3]};
            const f32x2 r0lo = gelu2(v0lo * A0lo + C0lo);
            const f32x2 r0hi = gelu2(v0hi * A0hi + C0hi);
            const f32x2 A1lo = glo * rstd1, A1hi = ghi * rstd1;
            const f32x2 C1lo = A1lo * (-mu1) + belo, C1hi = A1hi * (-mu1) + behi;
            const f32x2 v1lo = {acc1[mtl][0], acc1[mtl][1]};
            const f32x2 v1hi = {acc1[mtl][2], acc1[mtl][3]};
            const f32x2 r1lo = gelu2(v1lo * A1lo + C1lo);
            const f32x2 r1hi = gelu2(v1hi * A1hi + C1hi);
            if (L < 2) {
                const int wb = (int)((unsigned)((e << 9) + (mtg << 5) + (g << 3)) ^ swz);
                *(uint2*)(Hp0 + wb) = make_uint2(pack2(r0lo.x, r0lo.y), pack2(r0hi.x, r0hi.y));
                *(uint2*)(Hp1 + wb) = make_uint2(pack2(r1lo.x, r1lo.y), pack2(r1hi.x, r1hi.y));
            } else {
                acc0[mtl][0] = r0lo.x; acc0[mtl][1] = r0lo.y;
                acc0[mtl][2] = r0hi.x; acc0[mtl][3] = r0hi.y;
                acc1[mtl][0] = r1lo.x; acc1[mtl][1] = r1lo.y;
                acc1[mtl][2] = r1hi.x; acc1[mtl][3] = r1hi.y;
            }
        }
        if (L < 2) __syncthreads();      // pair partner's H writes visible
    }

    // ---- max over 16 edges (DPP row reduce) + bounce to Sb (Hl is dead) ----
#pragma unroll
    for (int mtl = 0; mtl < 8; ++mtl) {
#pragma unroll
        for (int i = 0; i < 4; ++i) {
            acc0[mtl][i] = dpp_rowmax16(acc0[mtl][i]);
            acc1[mtl][i] = dpp_rowmax16(acc1[mtl][i]);
        }
    }
    float* Sb0 = (float*)Hp0;
    float* Sb1 = (float*)Hp1;
#pragma unroll
    for (int mtl = 0; mtl < 8; ++mtl) {
        if (e == mtl) {
            const int fo = (((wq << 3) + mtl) << 4) + (g << 2);
            *(float4*)(Sb0 + fo) = *(const float4*)&acc0[mtl];
            *(float4*)(Sb1 + fo) = *(const float4*)&acc1[mtl];
        }
    }
    __syncthreads();

    // ---- final epilogue: agg from Sb, shortcut (incl bs) from d_out ----
    const int f0 = 16 * e + (g << 2);
    const float* SbO = wq ? Sb1 : Sb0;
    const float4 agg = *(const float4*)(SbO + f0);
    float* op = out + (size_t)p * E_ + f0;
    const float4 ssc = *(const float4*)op;
    f32x2 elo = {agg.x + ssc.x, agg.y + ssc.y};
    f32x2 ehi = {agg.z + ssc.z, agg.w + ssc.w};
    const f32x2 olo = gelu2(elo);
    const f32x2 ohi = gelu2(ehi);
    float4 o;
    o.x = olo.x; o.y = olo.y; o.z = ohi.x; o.w = ohi.y;
    *(float4*)op = o;
}

extern "C" void kernel_launch(void* const* d_in, const int* in_sizes, int n_in,
                              void* d_out, int out_size, void* d_ws, size_t ws_size,
                              hipStream_t stream) {
    const float* x      = (const float*)d_in[0];
    const float* coords = (const float*)d_in[1];
    const float* W1  = (const float*)d_in[2];
    const float* b1  = (const float*)d_in[3];
    const float* g1  = (const float*)d_in[4];
    const float* be1 = (const float*)d_in[5];
    const float* W2  = (const float*)d_in[6];
    const float* b2  = (const float*)d_in[7];
    const float* g2  = (const float*)d_in[8];
    const float* be2 = (const float*)d_in[9];
    const float* W3  = (const float*)d_in[10];
    const float* b3  = (const float*)d_in[11];
    const float* g3  = (const float*)d_in[12];
    const float* be3 = (const float*)d_in[13];
    const float* Ws  = (const float*)d_in[14];
    const float* bs  = (const float*)d_in[15];
    float* out = (float*)d_out;

    int*   knn = (int*)d_ws;                          // 1 MiB
    short* WF  = (short*)((char*)d_ws + (1 << 20));   // 384 KiB bf16 fragments

    prep_kernel<<<2048 + 48 + 128, 512, 0, stream>>>(
        coords, x, W1, W2, W3, Ws, bs, knn, WF, out);
    edgeconv_mfma<<<(B_ * N_) / 4, 256, 0, stream>>>(
        x, knn, WF, b1, g1, be1, b2, g2, be2, b3, g3, be3, out);
}

// Round 16
// 295.883 us; speedup vs baseline: 1.0206x; 1.0206x over previous
//
#include <hip/hip_runtime.h>
#include <hip/hip_bf16.h>
#include <math.h>

#define B_ 8
#define N_ 2048
#define D_ 128
#define E_ 256
#define K_ 16
#define LN_EPS 1e-5f

typedef short bf16x8 __attribute__((ext_vector_type(8)));
typedef float f32x4 __attribute__((ext_vector_type(4)));
typedef float f32x2 __attribute__((ext_vector_type(2)));

// ---------------------------------------------------------------------------
// Reference-matching f32 distance (expanded form, no FMA contraction).
// ---------------------------------------------------------------------------
__device__ __forceinline__ float sq3_ref(float x, float y, float z) {
#pragma clang fp contract(off)
    float s = x * x + y * y;
    s = s + z * z;
    return s;
}
__device__ __forceinline__ float d2_ref(float qx, float qy, float qz, float sqq,
                                        float mx, float my, float mz, float sqm) {
#pragma clang fp contract(off)
    float dot = mx * qx + my * qy;
    dot = dot + mz * qz;
    float t1 = sqq + sqm;
    float t2 = 2.0f * dot;
    float d2 = t1 - t2;
    return d2 > 0.0f ? d2 : 0.0f;
}

// pack two f32 -> bf16x2 dword (compiler fuses to v_cvt_pk_bf16_f32)
__device__ __forceinline__ unsigned pack2(float a, float b) {
    union { __hip_bfloat162 h2; unsigned u; } cv;
    cv.h2 = __float22bfloat162_rn(float2{a, b});
    return cv.u;
}

// tanh-form GELU pair via sigmoid identity, f32x2 vector form (v_pk_* ops)
__device__ __forceinline__ f32x2 gelu2(f32x2 v) {
    const f32x2 w = v * v;
    f32x2 inner = w * 0.044715f;
    inner.x += 1.0f; inner.y += 1.0f;
    const f32x2 ue = (v * -2.3022083f) * inner;      // -2u*log2e
    f32x2 t;
    t.x = __builtin_amdgcn_exp2f(ue.x);
    t.y = __builtin_amdgcn_exp2f(ue.y);
    f32x2 den = t;
    den.x += 1.0f; den.y += 1.0f;
    f32x2 r;
    r.x = __builtin_amdgcn_rcpf(den.x);
    r.y = __builtin_amdgcn_rcpf(den.y);
    return v * r;
}

// max over the 16 contiguous lanes of a DPP row (e = lane&15), VALU-only.
__device__ __forceinline__ float dpp_rowmax16(float v) {
    int x = __float_as_int(v);
    v = fmaxf(v, __int_as_float(__builtin_amdgcn_mov_dpp(x, 0xB1, 0xF, 0xF, true)));
    x = __float_as_int(v);
    v = fmaxf(v, __int_as_float(__builtin_amdgcn_mov_dpp(x, 0x4E, 0xF, 0xF, true)));
    x = __float_as_int(v);
    v = fmaxf(v, __int_as_float(__builtin_amdgcn_mov_dpp(x, 0x141, 0xF, 0xF, true)));
    x = __float_as_int(v);
    v = fmaxf(v, __int_as_float(__builtin_amdgcn_mov_dpp(x, 0x140, 0xF, 0xF, true)));
    return v;
}

// ---------------------------------------------------------------------------
// Kernel 1 (fused prep), 512 threads/block, heterogeneous grid:
//   blocks [0, 2048)    : kNN top-16 radix select (8 queries/block)
//   blocks [2048, 2096) : W1/W2/W3 -> bf16 MFMA A-fragment prepack (8/block)
//   blocks [2096, 2224) : shortcut out = x @ Ws + bs via MFMA, A-fragments
//                         packed inline from global f32 Ws (no WF dependency)
// All three parts independent -> no intra-kernel ordering needed.
// ---------------------------------------------------------------------------
__global__ __launch_bounds__(512) void prep_kernel(
    const float* __restrict__ coords, const float* __restrict__ x,
    const float* __restrict__ W1, const float* __restrict__ W2,
    const float* __restrict__ W3, const float* __restrict__ Ws,
    const float* __restrict__ bs,
    int* __restrict__ knn_out, short* __restrict__ WF, float* __restrict__ out)
{
    __shared__ float smem[4 * N_ + 8];
    const int bid = blockIdx.x;
    const int tid = threadIdx.x;

    if (bid < 2048) {
        // ================= kNN top-16 radix select =================
        float (*lc)[N_] = (float(*)[N_])smem;
        float* lsq = smem + 3 * N_;
        int* cnt = (int*)(smem + 4 * N_);
        const int wave = tid >> 6;
        const int lane = tid & 63;
        const int p = bid * 8 + wave;
        const int b = p >> 11;
        const int n0 = p & (N_ - 1);
        const float* cb = coords + (size_t)b * N_ * 3;
        for (int i = tid; i < N_ * 3; i += 512) {
            int n = i / 3, c = i - 3 * n;
            lc[c][n] = cb[i];
        }
        __syncthreads();
        for (int n = tid; n < N_; n += 512) lsq[n] = sq3_ref(lc[0][n], lc[1][n], lc[2][n]);
        __syncthreads();

        const float qx = lc[0][n0], qy = lc[1][n0], qz = lc[2][n0], sqq = lsq[n0];
        unsigned key[32];
#pragma unroll
        for (int j = 0; j < 32; ++j) {
            const int m = j * 64 + lane;
            key[j] = __float_as_uint(d2_ref(qx, qy, qz, sqq, lc[0][m], lc[1][m], lc[2][m], lsq[m]));
        }

        unsigned prefix = 0;
        int rem = K_, setc = N_, bshift = 0;
        bool bounded = false;
        for (int bit = 31; bit >= 0; --bit) {
            const unsigned want = prefix << 1;
            int c = 0;
#pragma unroll
            for (int j = 0; j < 32; ++j) c += ((key[j] >> bit) == want) ? 1 : 0;
            for (int off = 1; off < 64; off <<= 1) c += __shfl_xor(c, off, 64);
            if (rem <= c) { prefix = want; setc = c; }
            else          { prefix = want | 1u; rem -= c; setc -= c; }
            bshift = bit;
            if (setc == rem) { bounded = true; break; }
        }

        if (lane == 0) cnt[wave] = 0;
        int* op = knn_out + (size_t)p * K_;
        const unsigned long long BE = bounded ? (((unsigned long long)prefix + 1ull) << bshift)
                                              : (unsigned long long)prefix;
#pragma unroll
        for (int j = 0; j < 32; ++j) {
            if ((unsigned long long)key[j] < BE) {
                int s = atomicAdd(&cnt[wave], 1);
                op[s] = j * 64 + lane;
            }
        }
        if (!bounded) {
            const unsigned V = prefix;
#pragma unroll
            for (int j = 0; j < 32; ++j) {
                if (rem > 0) {
                    unsigned long long mask = __ballot(key[j] == V);
                    int below = __popcll(mask & ((1ull << lane) - 1ull));
                    if (key[j] == V && below < rem) {
                        int s = atomicAdd(&cnt[wave], 1);
                        op[s] = j * 64 + lane;
                    }
                    rem -= __popcll(mask);
                }
            }
        }
    } else if (bid < 2096) {
        // ================= W prepack: layers only (384 units, 8 per block) =====
        const int unit = (bid - 2048) * 8 + (tid >> 6);  // 0..383
        const int lane = tid & 63;
        const int g = lane >> 4, e = lane & 15;
        const int L = unit >> 7;
        const int t = unit & 127;                        // t = kt*16 + mt
        const int kt = t >> 4, mt = t & 15;
        const float* W = (L == 0) ? W1 : (L == 1) ? W2 : W3;
        const int f = 16 * mt + e;
        unsigned v[4];
#pragma unroll
        for (int i2 = 0; i2 < 4; ++i2) {
            const int k = 32 * kt + 8 * g + 2 * i2;
            v[i2] = pack2(W[(size_t)k * E_ + f], W[(size_t)(k + 1) * E_ + f]);
        }
        uint4 u; u.x = v[0]; u.y = v[1]; u.z = v[2]; u.w = v[3];
        *reinterpret_cast<uint4*>(WF + ((size_t)unit * 64 + lane) * 8) = u;
    } else {
        // ================= shortcut: out = x @ Ws + bs (MFMA, inline A-pack) ===
        const int wave = tid >> 6;
        const int lane = tid & 63;
        const int e = lane & 15;
        const int g = lane >> 4;
        const int p0 = ((bid - 2096) * 8 + wave) * 16;   // 16 points per wave
        const float* xr = x + (size_t)(p0 + e) * D_;

        f32x4 acc[16];
        const f32x4 z4 = {0.f, 0.f, 0.f, 0.f};
#pragma unroll
        for (int mt = 0; mt < 16; ++mt) acc[mt] = z4;

#pragma unroll
        for (int kt = 0; kt < 4; ++kt) {
            const float4 xa = *(const float4*)(xr + kt * 32 + g * 8);
            const float4 xb = *(const float4*)(xr + kt * 32 + g * 8 + 4);
            union { unsigned u[4]; bf16x8 v; } bx;
            bx.u[0] = pack2(xa.x, xa.y); bx.u[1] = pack2(xa.z, xa.w);
            bx.u[2] = pack2(xb.x, xb.y); bx.u[3] = pack2(xb.z, xb.w);
            const float* Wsrc = Ws + (size_t)(32 * kt + 8 * g) * E_ + e;
#pragma unroll
            for (int mt = 0; mt < 16; ++mt) {
                const float* wp = Wsrc + 16 * mt;
                float w[8];
#pragma unroll
                for (int i = 0; i < 8; ++i) w[i] = wp[(size_t)i * E_];
                union { unsigned u[4]; bf16x8 v; } a;
                a.u[0] = pack2(w[0], w[1]); a.u[1] = pack2(w[2], w[3]);
                a.u[2] = pack2(w[4], w[5]); a.u[3] = pack2(w[6], w[7]);
                acc[mt] = __builtin_amdgcn_mfma_f32_16x16x32_bf16(a.v, bx.v, acc[mt], 0, 0, 0);
            }
        }
#pragma unroll
        for (int mt = 0; mt < 16; ++mt) {
            const float4 bsv = *(const float4*)(bs + 16 * mt + 4 * g);
            float4 o;
            o.x = acc[mt][0] + bsv.x; o.y = acc[mt][1] + bsv.y;
            o.z = acc[mt][2] + bsv.z; o.w = acc[mt][3] + bsv.w;
            *(float4*)(out + (size_t)(p0 + e) * E_ + 16 * mt + 4 * g) = o;
        }
    }
}

// ---------------------------------------------------------------------------
// Kernel 2: fused edge-MLP (best-measured config, R13/R14). WAVE-PAIR
// mt-split, single-buffered 16 KiB Wbuf, current-layer LN params in LDS.
// LDS 52 KiB + launch_bounds(256,3) -> 3 blocks/CU (measured: 84 VGPR, 32% occ,
// 233 us). Double-buffer (2 blk/CU)=260, direct-global-A=242, reg-cap-only or
// LDS-fit-only=286: both halves of the occupancy move must land together.
// ---------------------------------------------------------------------------
#define WCHUNKS 24

__device__ __forceinline__ void stage_chunk(const short* __restrict__ WF,
                                            short* __restrict__ dst,
                                            int c, int wave, int lane) {
    const short* src = WF + ((size_t)(c << 4) << 9);    // fragment 16c, *512 shorts
#pragma unroll
    for (int i = 0; i < 4; ++i) {
        const int slot = (i << 8) + (wave << 6);        // wave-uniform slot base
        const short* gp = src + ((size_t)(slot + lane) << 3);
        short* lp = dst + ((size_t)slot << 3);
        __builtin_amdgcn_global_load_lds(
            (const __attribute__((address_space(1))) void*)gp,
            (__attribute__((address_space(3))) void*)lp, 16, 0, 0);
    }
}

__global__ __launch_bounds__(256, 3) void edgeconv_mfma(
    const float* __restrict__ x, const int* __restrict__ knn,
    const short* __restrict__ WF,
    const float* __restrict__ b1, const float* __restrict__ g1, const float* __restrict__ be1,
    const float* __restrict__ b2, const float* __restrict__ g2, const float* __restrict__ be2,
    const float* __restrict__ b3, const float* __restrict__ g3, const float* __restrict__ be3,
    float* __restrict__ out)
{
    __shared__ short Hl[2][2][4096];    // 32 KiB: [pair][point][16e x 256f bf16] swizzled
    __shared__ short Wbuf[8192];        // 16 KiB: SINGLE-buffered W chunk
    __shared__ float4 Xch[2][2][16];    // 1 KiB: LN partial exchange
    __shared__ float Pl[768];           // 3 KiB: CURRENT layer's b,g,be
    const int tid  = threadIdx.x;
    const int wave = tid >> 6;
    const int lane = tid & 63;
    const int wq = wave & 1;            // parity within pair (feature-half owner)
    const int pr = wave >> 1;           // pair index
    const int e = lane & 15;
    const int g = lane >> 4;
    const int p = blockIdx.x * 4 + wave;   // own point
    const int b = p >> 11;
    const int n = p & (N_ - 1);
    const unsigned swz = (unsigned)((e & 7) << 4);
    char* Hown = (char*)&Hl[pr][wq][0];
    char* Hp0  = (char*)&Hl[pr][0][0];
    char* Hp1  = (char*)&Hl[pr][1][0];

    // ---- edge build (own point): H[e][0:128]=central, H[e][128:256]=nbr-central
    {
        const float4* xr = (const float4*)(x + ((size_t)b * N_ + n) * D_);
        const int nb = knn[(size_t)p * K_ + e];
        const float4* nr = (const float4*)(x + ((size_t)b * N_ + nb) * D_);
#pragma unroll
        for (int c2 = 0; c2 < 8; ++c2) {
            const float4 cv = xr[8 * g + c2];
            const float4 nv = nr[8 * g + c2];
            const int base = (e << 9) + (g << 6) + (c2 << 3);
            *(uint2*)(Hown + (base ^ swz)) = make_uint2(pack2(cv.x, cv.y), pack2(cv.z, cv.w));
            *(uint2*)(Hown + ((base + 256) ^ swz)) =
                make_uint2(pack2(nv.x - cv.x, nv.y - cv.y), pack2(nv.z - cv.z, nv.w - cv.w));
        }
    }

    f32x4 acc0[8], acc1[8];             // [mtl] for point0 / point1
    const f32x4 z4 = {0.f, 0.f, 0.f, 0.f};

    for (int L = 0; L < 3; ++L) {
        const float* bL  = (L == 0) ? b1  : (L == 1) ? b2  : b3;
        const float* gL  = (L == 0) ? g1  : (L == 1) ? g2  : g3;
        const float* beL = (L == 0) ? be1 : (L == 1) ? be2 : be3;
#pragma unroll
        for (int mtl = 0; mtl < 8; ++mtl) { acc0[mtl] = z4; acc1[mtl] = z4; }

        for (int kt = 0; kt < 8; ++kt) {
            const int c = L * 8 + kt;
            __syncthreads();                       // Wbuf free; H/pass-2 writes visible
            const int offB = (int)((unsigned)((e << 9) + (kt << 6) + (g << 4)) ^ swz);
            const bf16x8 Bc0 = *(const bf16x8*)(Hp0 + offB);
            const bf16x8 Bc1 = *(const bf16x8*)(Hp1 + offB);
            stage_chunk(WF, Wbuf, c, wave, lane);
            asm volatile("s_waitcnt vmcnt(0)" ::: "memory");
            __syncthreads();                       // chunk landed for all waves
            if (kt == 0) {                         // refill current-layer LN params
                Pl[tid]       = bL[tid];
                Pl[256 + tid] = gL[tid];
                Pl[512 + tid] = beL[tid];
            }
            __builtin_amdgcn_s_setprio(1);
#pragma unroll
            for (int mtl = 0; mtl < 8; ++mtl) {
                const bf16x8 a = *(const bf16x8*)(Wbuf + ((((wq << 3) + mtl) << 6) + lane) * 8);
                acc0[mtl] = __builtin_amdgcn_mfma_f32_16x16x32_bf16(a, Bc0, acc0[mtl], 0, 0, 0);
                acc1[mtl] = __builtin_amdgcn_mfma_f32_16x16x32_bf16(a, Bc1, acc1[mtl], 0, 0, 0);
            }
            __builtin_amdgcn_s_setprio(0);
        }

        // ---- LN pass 1: bias + partial sums (pk form) ----
        f32x2 s2_0 = {0.f, 0.f}, q2_0 = {0.f, 0.f};
        f32x2 s2_1 = {0.f, 0.f}, q2_1 = {0.f, 0.f};
#pragma unroll
        for (int mtl = 0; mtl < 8; ++mtl) {
            const int mtg = (wq << 3) + mtl;
            const float4 bv = *(const float4*)(Pl + mtg * 16 + (g << 2));
            const f32x2 blo = {bv.x, bv.y}, bhi = {bv.z, bv.w};
            f32x2 a0lo = {acc0[mtl][0], acc0[mtl][1]};
            f32x2 a0hi = {acc0[mtl][2], acc0[mtl][3]};
            f32x2 a1lo = {acc1[mtl][0], acc1[mtl][1]};
            f32x2 a1hi = {acc1[mtl][2], acc1[mtl][3]};
            a0lo = a0lo + blo; a0hi = a0hi + bhi;
            a1lo = a1lo + blo; a1hi = a1hi + bhi;
            s2_0 = s2_0 + a0lo; s2_0 = s2_0 + a0hi;
            q2_0 = q2_0 + a0lo * a0lo; q2_0 = q2_0 + a0hi * a0hi;
            s2_1 = s2_1 + a1lo; s2_1 = s2_1 + a1hi;
            q2_1 = q2_1 + a1lo * a1lo; q2_1 = q2_1 + a1hi * a1hi;
            acc0[mtl][0] = a0lo.x; acc0[mtl][1] = a0lo.y;
            acc0[mtl][2] = a0hi.x; acc0[mtl][3] = a0hi.y;
            acc1[mtl][0] = a1lo.x; acc1[mtl][1] = a1lo.y;
            acc1[mtl][2] = a1hi.x; acc1[mtl][3] = a1hi.y;
        }
        float s0 = s2_0.x + s2_0.y, q0 = q2_0.x + q2_0.y;
        float s1 = s2_1.x + s2_1.y, q1 = q2_1.x + q2_1.y;
        s0 += __shfl_xor(s0, 16, 64); s0 += __shfl_xor(s0, 32, 64);
        q0 += __shfl_xor(q0, 16, 64); q0 += __shfl_xor(q0, 32, 64);
        s1 += __shfl_xor(s1, 16, 64); s1 += __shfl_xor(s1, 32, 64);
        q1 += __shfl_xor(q1, 16, 64); q1 += __shfl_xor(q1, 32, 64);
        if (lane < 16) Xch[pr][wq][e] = make_float4(s0, q0, s1, q1);
        __syncthreads();
        const float4 oX = Xch[pr][wq ^ 1][e];
        const float mu0 = (s0 + oX.x) * (1.0f / 256.0f);
        const float var0 = fmaf(-mu0, mu0, (q0 + oX.y) * (1.0f / 256.0f));
        const float rstd0 = rsqrtf(var0 + LN_EPS);
        const float mu1 = (s1 + oX.z) * (1.0f / 256.0f);
        const float var1 = fmaf(-mu1, mu1, (q1 + oX.w) * (1.0f / 256.0f));
        const float rstd1 = rsqrtf(var1 + LN_EPS);

        // ---- LN pass 2 + GELU (pk form) ----
#pragma unroll
        for (int mtl = 0; mtl < 8; ++mtl) {
            const int mtg = (wq << 3) + mtl;
            const float4 gv  = *(const float4*)(Pl + 256 + mtg * 16 + (g << 2));
            const float4 bev = *(const float4*)(Pl + 512 + mtg * 16 + (g << 2));
            const f32x2 glo = {gv.x, gv.y}, ghi = {gv.z, gv.w};
            const f32x2 belo = {bev.x, bev.y}, behi = {bev.z, bev.w};
            const f32x2 A0lo = glo * rstd0, A0hi = ghi * rstd0;
            const f32x2 C0lo = A0lo * (-mu0) + belo, C0hi = A0hi * (-mu0) + behi;
            const f32x2 v0lo = {acc0[mtl][0], acc0[mtl][1]};
            const f32x2 v0hi = {acc0[mtl][2], acc0[mtl][3]};
            const f32x2 r0lo = gelu2(v0lo * A0lo + C0lo);
            const f32x2 r0hi = gelu2(v0hi * A0hi + C0hi);
            const f32x2 A1lo = glo * rstd1, A1hi = ghi * rstd1;
            const f32x2 C1lo = A1lo * (-mu1) + belo, C1hi = A1hi * (-mu1) + behi;
            const f32x2 v1lo = {acc1[mtl][0], acc1[mtl][1]};
            const f32x2 v1hi = {acc1[mtl][2], acc1[mtl][3]};
            const f32x2 r1lo = gelu2(v1lo * A1lo + C1lo);
            const f32x2 r1hi = gelu2(v1hi * A1hi + C1hi);
            if (L < 2) {
                const int wb = (int)((unsigned)((e << 9) + (mtg << 5) + (g << 3)) ^ swz);
                *(uint2*)(Hp0 + wb) = make_uint2(pack2(r0lo.x, r0lo.y), pack2(r0hi.x, r0hi.y));
                *(uint2*)(Hp1 + wb) = make_uint2(pack2(r1lo.x, r1lo.y), pack2(r1hi.x, r1hi.y));
            } else {
                acc0[mtl][0] = r0lo.x; acc0[mtl][1] = r0lo.y;
                acc0[mtl][2] = r0hi.x; acc0[mtl][3] = r0hi.y;
                acc1[mtl][0] = r1lo.x; acc1[mtl][1] = r1lo.y;
                acc1[mtl][2] = r1hi.x; acc1[mtl][3] = r1hi.y;
            }
        }
        // next phase's first __syncthreads makes H writes visible before B reads
    }

    // ---- max over 16 edges (DPP row reduce) + bounce to Sb (Hl is dead) ----
#pragma unroll
    for (int mtl = 0; mtl < 8; ++mtl) {
#pragma unroll
        for (int i = 0; i < 4; ++i) {
            acc0[mtl][i] = dpp_rowmax16(acc0[mtl][i]);
            acc1[mtl][i] = dpp_rowmax16(acc1[mtl][i]);
        }
    }
    float* Sb0 = (float*)Hp0;
    float* Sb1 = (float*)Hp1;
#pragma unroll
    for (int mtl = 0; mtl < 8; ++mtl) {
        if (e == mtl) {
            const int fo = (((wq << 3) + mtl) << 4) + (g << 2);
            *(float4*)(Sb0 + fo) = *(const float4*)&acc0[mtl];
            *(float4*)(Sb1 + fo) = *(const float4*)&acc1[mtl];
        }
    }
    __syncthreads();

    // ---- final epilogue: agg from Sb, shortcut (incl bs) from d_out ----
    const int f0 = 16 * e + (g << 2);
    const float* SbO = wq ? Sb1 : Sb0;
    const float4 agg = *(const float4*)(SbO + f0);
    float* op = out + (size_t)p * E_ + f0;
    const float4 ssc = *(const float4*)op;
    f32x2 elo = {agg.x + ssc.x, agg.y + ssc.y};
    f32x2 ehi = {agg.z + ssc.z, agg.w + ssc.w};
    const f32x2 olo = gelu2(elo);
    const f32x2 ohi = gelu2(ehi);
    float4 o;
    o.x = olo.x; o.y = olo.y; o.z = ohi.x; o.w = ohi.y;
    *(float4*)op = o;
}

extern "C" void kernel_launch(void* const* d_in, const int* in_sizes, int n_in,
                              void* d_out, int out_size, void* d_ws, size_t ws_size,
                              hipStream_t stream) {
    const float* x      = (const float*)d_in[0];
    const float* coords = (const float*)d_in[1];
    const float* W1  = (const float*)d_in[2];
    const float* b1  = (const float*)d_in[3];
    const float* g1  = (const float*)d_in[4];
    const float* be1 = (const float*)d_in[5];
    const float* W2  = (const float*)d_in[6];
    const float* b2  = (const float*)d_in[7];
    const float* g2  = (const float*)d_in[8];
    const float* be2 = (const float*)d_in[9];
    const float* W3  = (const float*)d_in[10];
    const float* b3  = (const float*)d_in[11];
    const float* g3  = (const float*)d_in[12];
    const float* be3 = (const float*)d_in[13];
    const float* Ws  = (const float*)d_in[14];
    const float* bs  = (const float*)d_in[15];
    float* out = (float*)d_out;

    int*   knn = (int*)d_ws;                          // 1 MiB
    short* WF  = (short*)((char*)d_ws + (1 << 20));   // 384 KiB bf16 fragments

    prep_kernel<<<2048 + 48 + 128, 512, 0, stream>>>(
        coords, x, W1, W2, W3, Ws, bs, knn, WF, out);
    edgeconv_mfma<<<(B_ * N_) / 4, 256, 0, stream>>>(
        x, knn, WF, b1, g1, be1, b2, g2, be2, b3, g3, be3, out);
}